// Round 11
// baseline (2175.499 us; speedup 1.0000x reference)
//
#include <hip/hip_runtime.h>
#include <hip/hip_bf16.h>

// FNO2d: B=16, CIN=20, H=W=256, WIDTH=64, M1=M2=16, NLAYERS=4, FC_HID=128, COUT=20
// Round 14: R13 win confirmed (2457->2128; conflicts 1.02e7->1.9e6). Remaining
// anomaly: pwcomb VGPR_Count=32 with VALUBusy*dur ~4.6x the static VALU count
// (proj's same ratio is ~1.6x) -> allocator squeezed to 32 VGPRs chasing
// 16-waves/SIMD occupancy that the 80KB LDS forbids (2 blocks/CU = 8 waves/SIMD
// cap). 32 < conv live set (~30) and << phase-C live set (~40+: fa[16]+acc2[20])
// -> remat/spill bloat. Fix: amdgpu_waves_per_eu(8,8) pins allocation at the
// LDS-feasible occupancy -> 64-VGPR budget actually used; conv unroll 2->4 to
// pipeline the s_load weight prefetch in the bigger budget.
//
// Per-sample workspace (floats): h 4,194,304 | T/G 524,288 | X2 65,536 | Y2 65,536
// = 4,849,664 floats (19.4 MB); CB=16 -> 310 MB.

#define HW_TOT 65536
#define PI2_256 0.024543692606170259758f  // 2*pi/256

__device__ __forceinline__ float gelu_exact(float v) {
    return 0.5f * v * (1.0f + erff(v * 0.70710678118654752440f));
}
// Branch-free gelu: erf via Abramowitz-Stegun 7.1.26 (|abs err| <= 1.5e-7).
__device__ __forceinline__ float gelu_fast(float v) {
    float z  = v * 0.70710678118654752440f;
    float az = fabsf(z);
    float t  = __builtin_amdgcn_rcpf(fmaf(0.3275911f, az, 1.0f));
    float p  = t * (0.254829592f + t * (-0.284496736f + t * (1.421413741f +
               t * (-1.453152027f + t * 1.061405429f))));
    float e  = __expf(-az * az);
    float er = copysignf(1.0f - p * e, z);
    return 0.5f * v * (1.0f + er);
}
#define F4COMP(v, k) ((k)==0?(v).x:(k)==1?(v).y:(k)==2?(v).z:(v).w)

// ---------------- 1x1 conv (lift)
template<int CI, int CO, int WS>
__global__ void __launch_bounds__(256) conv1x1_kernel(
    const float* __restrict__ in, const float* __restrict__ w,
    const float* __restrict__ bias, float* __restrict__ out)
{
    const int b = blockIdx.y;
    const int p = blockIdx.x * 256 + threadIdx.x;
    const float* inp = in + (size_t)b * CI * HW_TOT + p;
    float acc[CO];
#pragma unroll
    for (int o = 0; o < CO; ++o) acc[o] = bias[o];
    for (int ci = 0; ci < CI; ++ci) {
        float hv = inp[(size_t)ci * HW_TOT];
#pragma unroll
        for (int o = 0; o < CO; ++o)
            acc[o] = fmaf(w[o * WS + ci], hv, acc[o]);
    }
    float* op = out + (size_t)b * CO * HW_TOT + p;
#pragma unroll
    for (int o = 0; o < CO; ++o) op[(size_t)o * HW_TOT] = acc[o];
}

// ---------------- forward DFT over y as GEMM: T[row*32 + 2ky+c] = sum_y h[row,y]*W[y][2ky+c]
// R8: twiddles rebuilt per 64-y chunk into Wc[64][32] (8KB); LDS 45KB.
__global__ void __launch_bounds__(256) dfty_kernel(
    const float* __restrict__ h, float* __restrict__ T)
{
    __shared__ float As[128][68];     // y-chunk of 64, padded (34.8 KB)
    __shared__ float Wc[64][32];      // per-chunk twiddles (8 KB)
    __shared__ float cs2[256], sn2[256];
    const int t = threadIdx.x;
    {
        float a = (float)t * PI2_256;
        cs2[t] = cosf(a); sn2[t] = sinf(a);
    }
    __syncthreads();

    const size_t rowbase = (size_t)blockIdx.x * 128;
    const int jg = t & 7, rg = t >> 3;
    float acc[4][4];
#pragma unroll
    for (int k = 0; k < 4; ++k)
#pragma unroll
        for (int q = 0; q < 4; ++q) acc[k][q] = 0.0f;

    for (int yc = 0; yc < 256; yc += 64) {
        if (yc) __syncthreads();   // protect As/Wc from previous iteration's readers
#pragma unroll
        for (int it = 0; it < 8; ++it) {
            int idx = t + 256 * it;
            int rr = idx >> 4, c4 = idx & 15;
            float4 v = *(const float4*)(h + (rowbase + rr) * 256 + yc + c4 * 4);
            *(float4*)&As[rr][c4 * 4] = v;
        }
        // build Wc for this chunk: Wc[yl][2ky+c] for y = yc+yl
#pragma unroll
        for (int it = 0; it < 8; ++it) {
            int i = t + 256 * it;
            int yl = i >> 5, j = i & 31, ky = j >> 1;
            int m = ((yc + yl) * ky) & 255;
            Wc[yl][j] = (j & 1) ? -sn2[m] : cs2[m];
        }
        __syncthreads();
#pragma unroll 2
        for (int yy = 0; yy < 64; yy += 4) {
            float4 wv[4], av[4];
#pragma unroll
            for (int q = 0; q < 4; ++q) wv[q] = *(const float4*)&Wc[yy + q][jg * 4];
#pragma unroll
            for (int k = 0; k < 4; ++k) av[k] = *(const float4*)&As[rg + 32 * k][yy];
#pragma unroll
            for (int k = 0; k < 4; ++k)
#pragma unroll
                for (int q = 0; q < 4; ++q) {
                    float a = F4COMP(av[k], q);
                    acc[k][0] = fmaf(a, wv[q].x, acc[k][0]);
                    acc[k][1] = fmaf(a, wv[q].y, acc[k][1]);
                    acc[k][2] = fmaf(a, wv[q].z, acc[k][2]);
                    acc[k][3] = fmaf(a, wv[q].w, acc[k][3]);
                }
        }
    }
#pragma unroll
    for (int k = 0; k < 4; ++k) {
        float4 v = make_float4(acc[k][0], acc[k][1], acc[k][2], acc[k][3]);
        *(float4*)&T[(rowbase + rg + 32 * k) * 32 + jg * 4] = v;
    }
}

// ---------------- forward DFT over x: X[bc,kxi,ky] = sum_x T[bc,x,ky] * e^{-2pi i kx x/256}
__global__ void __launch_bounds__(512) dft2_kernel(
    const float2* __restrict__ T2, float2* __restrict__ X2)
{
    __shared__ float cs[256], sn[256];
    const int t = threadIdx.x;
    if (t < 256) {
        float a = (float)t * PI2_256;
        cs[t] = cosf(a); sn[t] = sinf(a);
    }
    __syncthreads();
    const int bc = blockIdx.x;
    const int ky = t & 15, kxi = t >> 4;
    const int kx = (kxi < 16) ? kxi : (224 + kxi);
    const float2* Tp = T2 + (size_t)bc * 4096 + ky;
    float xr = 0.0f, xi = 0.0f;
    int m = 0;
    for (int x = 0; x < 256; ++x) {
        float2 tv = Tp[(size_t)x * 16];
        float c = cs[m], s = sn[m];
        xr = fmaf(tv.x, c, fmaf(tv.y, s, xr));
        xi = fmaf(tv.y, c, fmaf(-tv.x, s, xi));
        m = (m + kx) & 255;
    }
    X2[(size_t)bc * 512 + t] = make_float2(xr, xi);
}

// ---------------- complex mode mixing
__global__ void __launch_bounds__(512) mix_kernel(
    const float2* __restrict__ X2, float2* __restrict__ Y2,
    const float* __restrict__ w1r, const float* __restrict__ w1i,
    const float* __restrict__ w2r, const float* __restrict__ w2i, int layer)
{
    const int bo = blockIdx.x;
    const int b = bo >> 6, o = bo & 63;
    const int t = threadIdx.x;
    const int ky = t & 15, kxi = t >> 4;
    const bool top = (kxi < 16);
    const int kxm = top ? kxi : (kxi - 16);
    const float* wr = top ? w1r : w2r;
    const float* wi = top ? w1i : w2i;
    float yr = 0.0f, yi = 0.0f;
    for (int i = 0; i < 64; ++i) {
        float2 xv = X2[((size_t)(b * 64 + i) * 32 + kxi) * 16 + ky];
        size_t widx = (((size_t)layer * 64 + i) * 64 + o) * 256 + (kxm * 16 + ky);
        float wrv = wr[widx], wiv = wi[widx];
        yr = fmaf(xv.x, wrv, fmaf(-xv.y, wiv, yr));
        yi = fmaf(xv.x, wiv, fmaf(xv.y, wrv, yi));
    }
    Y2[((size_t)(b * 64 + o) * 32 + kxi) * 16 + ky] = make_float2(yr, yi);
}

// ---------------- inverse DFT over x
__global__ void __launch_bounds__(256) idft1_kernel(
    const float2* __restrict__ Y2, float2* __restrict__ G2)
{
    __shared__ float cs[256], sn[256];
    const int t = threadIdx.x;
    {
        float a = (float)t * PI2_256;
        cs[t] = cosf(a); sn[t] = sinf(a);
    }
    __syncthreads();
    const int bo = blockIdx.x >> 4;
    const int xc = blockIdx.x & 15;
    const int ky = t & 15, xo = t >> 4;
    const int x = xc * 16 + xo;
    const float2* Yp = Y2 + (size_t)bo * 512 + ky;
    float gr = 0.0f, gi = 0.0f;
    for (int kxi = 0; kxi < 32; ++kxi) {
        float2 yv = Yp[(size_t)kxi * 16];
        int kx = (kxi < 16) ? kxi : (224 + kxi);
        int m = (kx * x) & 255;
        float c = cs[m], s = sn[m];
        gr = fmaf(yv.x, c, fmaf(-yv.y, s, gr));
        gi = fmaf(yv.x, s, fmaf(yv.y, c, gi));
    }
    G2[((size_t)bo * 256 + x) * 16 + ky] = make_float2(gr, gi);
}

// ---------------- fused pointwise conv + iDFT-y + add (+GELU | +projection).
// 1024 thr = 16 waves. Wave owns o-quad ow = 4w (wave-uniform -> conv weights
// via s_load_dwordx4 straight from pw_w); lane owns y-quad yq = 4*lane -> 4
// contiguous b128 + 4 s_loads per 64 FMA. Spectral: Gt broadcast b128, padded
// [32][68]; Pt from cs/sn tables in buf spare. LDS exactly 80KB -> 2 blocks/CU.
// R14: amdgpu_waves_per_eu(8,8) pins the allocator at the LDS-feasible 8
// waves/EU so it uses the 64-VGPR budget (R13 chose 32 -> remat/spill bloat,
// VALUBusy*dur 4.6x static count); conv unroll 4 pipelines s_load prefetch.
// FUSE=1 (l=3): phase C projection: hn[64][260] overlay, wave-uniform fc1/fc2
// s_load GEMM, red[4][20][256] one-barrier reduction, coalesced out.
template<int FUSE>
__global__ void __launch_bounds__(1024)
__attribute__((amdgpu_waves_per_eu(8, 8)))
pwcomb_kernel(
    float* __restrict__ h, const float2* __restrict__ G2,
    const float* __restrict__ pw_w, const float* __restrict__ pw_b,
    int layer, int do_gelu,
    const float* __restrict__ w1t, const float* __restrict__ fb1,
    const float* __restrict__ fw2, const float* __restrict__ fb2,
    float* __restrict__ out)
{
    __shared__ float buf[20480];                       // 80 KB union
    float (*hs)[256] = (float (*)[256])buf;            // phase A: [64][256] = 16384
    float (*Gt)[68]  = (float (*)[68])buf;             // phase B: [32][68]  = 2176
    float (*Pt)[256] = (float (*)[256])(buf + 2176);   // phase B: [32][256] = 8192
    float* cs2 = buf + 16384;                          // [256] spare region
    float* sn2 = buf + 16640;                          // [256]
    const int t = threadIdx.x;
    const int b = blockIdx.x >> 8;
    const int x = blockIdx.x & 255;

    // tables (dead after phase-B staging; overlaid by phase C)
    if (t < 256) {
        float a = (float)t * PI2_256;
        cs2[t] = cosf(a); sn2[t] = sinf(a);
    }
    // ---- phase A staging: hs only (weights come via scalar path)
#pragma unroll
    for (int it = 0; it < 4; ++it) {
        int idx = t + 1024 * it;
        int ci = idx >> 6, c4 = idx & 63;
        float4 v = *(const float4*)(h + ((size_t)(b * 64 + ci) * 256 + x) * 256 + c4 * 4);
        *(float4*)&hs[ci][c4 * 4] = v;
    }
    __syncthreads();

    const int lane = t & 63;
    const int ow = __builtin_amdgcn_readfirstlane(t >> 6) * 4;  // wave-uniform o-quad
    const int yq = lane * 4;

    const float* bl = pw_b + layer * 64;
    float acc[4][4];   // [yj][oj]: output (ch = ow+oj, y = yq+yj)
#pragma unroll
    for (int oj = 0; oj < 4; ++oj) {
        float bv = bl[ow + oj];
#pragma unroll
        for (int yj = 0; yj < 4; ++yj) acc[yj][oj] = bv;
    }
    // conv part: K = 64 (hs b128 + s_load weights)
    const float* wbase = pw_w + layer * 4096;   // [o][ci]
#pragma unroll 4
    for (int cc = 0; cc < 64; cc += 4) {
        float4 wva[4];
#pragma unroll
        for (int oj = 0; oj < 4; ++oj)
            wva[oj] = *(const float4*)(wbase + (ow + oj) * 64 + cc);  // uniform -> s_load
#pragma unroll
        for (int k = 0; k < 4; ++k) {
            float4 hv = *(const float4*)&hs[cc + k][yq];
#pragma unroll
            for (int oj = 0; oj < 4; ++oj) {
                float w = F4COMP(wva[oj], k);
                acc[0][oj] = fmaf(hv.x, w, acc[0][oj]);
                acc[1][oj] = fmaf(hv.y, w, acc[1][oj]);
                acc[2][oj] = fmaf(hv.z, w, acc[2][oj]);
                acc[3][oj] = fmaf(hv.w, w, acc[3][oj]);
            }
        }
    }
    __syncthreads();   // all hs reads done -> safe to overlay Gt/Pt

    // ---- phase B staging: Gt from G2 (padded rows, 4-way); Pt from tables
    {
        int o = t >> 4, ky = t & 15;
        float2 g = G2[((size_t)(b * 64 + o) * 256 + x) * 16 + ky];
        Gt[2 * ky][o] = g.x;
        Gt[2 * ky + 1][o] = g.y;
    }
    const float inv = 1.0f / 65536.0f;
#pragma unroll
    for (int it = 0; it < 8; ++it) {
        int i = t + 1024 * it;
        int jp = i >> 8, y = i & 255, ky = jp >> 1;
        int m = (ky * y) & 255;
        float wk = (ky == 0) ? inv : 2.0f * inv;
        Pt[jp][y] = (jp & 1) ? -wk * sn2[m] : wk * cs2[m];
    }
    __syncthreads();

    // spectral part: K = 32 (Pt contiguous b128 + Gt broadcast b128)
#pragma unroll 4
    for (int jp = 0; jp < 32; ++jp) {
        float4 pv = *(const float4*)&Pt[jp][yq];
        float4 gv = *(const float4*)&Gt[jp][ow];   // uniform addr -> broadcast
#pragma unroll
        for (int yj = 0; yj < 4; ++yj) {
            float a = F4COMP(pv, yj);
            acc[yj][0] = fmaf(a, gv.x, acc[yj][0]);
            acc[yj][1] = fmaf(a, gv.y, acc[yj][1]);
            acc[yj][2] = fmaf(a, gv.z, acc[yj][2]);
            acc[yj][3] = fmaf(a, gv.w, acc[yj][3]);
        }
    }

    if (!FUSE) {
        // epilogue: gelu + store; lane-consecutive y -> 1KB/wave coalesced
#pragma unroll
        for (int oj = 0; oj < 4; ++oj) {
            float4 v = make_float4(acc[0][oj], acc[1][oj], acc[2][oj], acc[3][oj]);
            if (do_gelu) {
                v.x = gelu_fast(v.x); v.y = gelu_fast(v.y);
                v.z = gelu_fast(v.z); v.w = gelu_fast(v.w);
            }
            *(float4*)&h[((size_t)(b * 64 + ow + oj) * 256 + x) * 256 + yq] = v;
        }
        return;
    }

    // ---- phase C (l=3): projection. h_final tile -> buf as hn[64][260] (padded).
    __syncthreads();   // Pt/Gt reads done -> safe to overlay hn (tables dead too)
#pragma unroll
    for (int oj = 0; oj < 4; ++oj) {
        float4 v = make_float4(acc[0][oj], acc[1][oj], acc[2][oj], acc[3][oj]);
        *(float4*)&buf[(ow + oj) * 260 + yq] = v;   // hn[ch][y], pad 260
    }
    __syncthreads();

    const int px = t & 255;
    const int wf = __builtin_amdgcn_readfirstlane(t >> 8);  // 0..3, wave-uniform
    float acc2[20];
#pragma unroll
    for (int o = 0; o < 20; ++o) acc2[o] = (wf == 0) ? fb2[o] : 0.0f;

#pragma unroll
    for (int pass = 0; pass < 2; ++pass) {
        const int hd0 = wf * 32 + pass * 16;
        float fa[16];
#pragma unroll
        for (int k = 0; k < 16; ++k) fa[k] = fb1[hd0 + k];
#pragma unroll 2
        for (int ci = 0; ci < 64; ++ci) {
            float a = buf[ci * 260 + px];             // lanes px-consecutive: conflict-free
            const float* wr = w1t + ci * 128 + hd0;   // wave-uniform -> s_load
#pragma unroll
            for (int k = 0; k < 16; ++k) fa[k] = fmaf(wr[k], a, fa[k]);
        }
#pragma unroll
        for (int k = 0; k < 16; ++k) fa[k] = gelu_fast(fa[k]);
#pragma unroll
        for (int o = 0; o < 20; ++o) {
            const float* w2r = fw2 + o * 128 + hd0;   // wave-uniform -> s_load
            float s0 = 0.0f, s1 = 0.0f;
#pragma unroll
            for (int k = 0; k < 16; k += 2) {
                s0 = fmaf(w2r[k], fa[k], s0);
                s1 = fmaf(w2r[k + 1], fa[k + 1], s1);
            }
            acc2[o] += s0 + s1;
        }
    }
    __syncthreads();   // all hn reads done -> safe to overlay red[4][20][256]
#pragma unroll
    for (int o = 0; o < 20; ++o) buf[(wf * 20 + o) * 256 + px] = acc2[o];
    __syncthreads();

    float* op = out + (size_t)b * 20 * HW_TOT + x * 256 + px;
#pragma unroll
    for (int j = 0; j < 5; ++j) {
        int o = wf * 5 + j;
        float s = buf[o * 256 + px] + buf[(20 + o) * 256 + px]
                + buf[(40 + o) * 256 + px] + buf[(60 + o) * 256 + px];
        op[(size_t)o * HW_TOT] = s;   // lanes px-consecutive: coalesced
    }
}

// ---------------- tiny transpose: w1t[ci][hd] = fc1_w[hd][ci]  (64 x 128)
__global__ void __launch_bounds__(256) transpose_w1_kernel(
    const float* __restrict__ w1, float* __restrict__ w1t)
{
    int i = blockIdx.x * 256 + threadIdx.x;   // 8192 elements
    int ci = i >> 7, hd = i & 127;
    w1t[i] = w1[hd * 64 + ci];
}

extern "C" void kernel_launch(void* const* d_in, const int* in_sizes, int n_in,
                              void* d_out, int out_size, void* d_ws, size_t ws_size,
                              hipStream_t stream)
{
    const float* x     = (const float*)d_in[0];
    const float* w1r   = (const float*)d_in[1];
    const float* w1i   = (const float*)d_in[2];
    const float* w2r   = (const float*)d_in[3];
    const float* w2i   = (const float*)d_in[4];
    const float* pw_w  = (const float*)d_in[5];
    const float* pw_b  = (const float*)d_in[6];
    const float* fc0_w = (const float*)d_in[7];
    const float* fc0_b = (const float*)d_in[8];
    const float* fc1_w = (const float*)d_in[9];
    const float* fc1_b = (const float*)d_in[10];
    const float* fc2_w = (const float*)d_in[11];
    const float* fc2_b = (const float*)d_in[12];
    float* out = (float*)d_out;
    float* ws  = (float*)d_ws;

    const size_t per_sample_floats = 4849664;
    int CB = 16;
    while (CB > 1 && (size_t)CB * per_sample_floats * 4 > ws_size) CB >>= 1;

    float*  h  = ws;
    float*  T  = ws + (size_t)CB * 4194304;
    float2* T2 = (float2*)T;
    float2* X2 = (float2*)(T + (size_t)CB * 524288);
    float2* Y2 = (float2*)(T + (size_t)CB * 524288 + (size_t)CB * 65536);
    float2* G2 = T2;   // reuse

    for (int c0 = 0; c0 < 16; c0 += CB) {
        const float* xc = x + (size_t)c0 * 20 * HW_TOT;
        float* oc = out + (size_t)c0 * 20 * HW_TOT;

        conv1x1_kernel<20, 64, 20>
            <<<dim3(256, CB), 256, 0, stream>>>(xc, fc0_w, fc0_b, h);

        for (int l = 0; l < 3; ++l) {
            dfty_kernel <<<CB * 128, 256, 0, stream>>>(h, T);
            dft2_kernel <<<CB * 64, 512, 0, stream>>>(T2, X2);
            mix_kernel  <<<CB * 64, 512, 0, stream>>>(X2, Y2, w1r, w1i, w2r, w2i, l);
            idft1_kernel<<<CB * 64 * 16, 256, 0, stream>>>(Y2, G2);
            pwcomb_kernel<0><<<CB * 256, 1024, 0, stream>>>(
                h, G2, pw_w, pw_b, l, 1,
                nullptr, nullptr, nullptr, nullptr, nullptr);
        }

        // layer 3: spectral pipeline, then fused pwcomb+projection
        dfty_kernel <<<CB * 128, 256, 0, stream>>>(h, T);
        dft2_kernel <<<CB * 64, 512, 0, stream>>>(T2, X2);
        mix_kernel  <<<CB * 64, 512, 0, stream>>>(X2, Y2, w1r, w1i, w2r, w2i, 3);
        idft1_kernel<<<CB * 64 * 16, 256, 0, stream>>>(Y2, G2);
        // Y2 region is dead after idft1 l=3: reuse for w1^T (G2/T untouched)
        float* w1t_buf = (float*)Y2;
        transpose_w1_kernel<<<32, 256, 0, stream>>>(fc1_w, w1t_buf);
        pwcomb_kernel<1><<<CB * 256, 1024, 0, stream>>>(
            h, G2, pw_w, pw_b, 3, 0,
            w1t_buf, fc1_b, fc2_w, fc2_b, oc);
    }
}